// Round 4
// baseline (252.926 us; speedup 1.0000x reference)
//
#include <hip/hip_runtime.h>
#include <math.h>

// SuperLoss: tau = mean(loss); y = max(-1/e, 5d), d = l - tau;
// w = W0(y); unclamped: out = d*e^{-w} + 0.1 w^2 = 0.1*w*(w+2)  [w e^w = y = 5d]
// clamped (5d < -1/e): w = -1, sigma = e -> out = e*d + 0.1  (exact closed form)
//
// W0 via single Pade[2/2] init in branch variable p = sqrt(2(e*y+1)):
//   (w+1)/p ~= (1 + 0.5p + 0.018055p^2)/(1 + 0.833323p + 0.143051p^2)
// max init err 0.0133 over p in [0,3.95]; one Newton step -> <= 7e-5.
//
// v4b: v4 with the nontemporal-store type fixed (builtin requires a native
// clang vector type, not HIP_vector_type -> use ext_vector_type(4) float).
//   - K2 grid 2048 persistent blocks: redundant 8 KB tau-prologue runs once
//     per resident block instead of 4x per CU slot.
//   - Explicit unroll on both streaming loops for more outstanding loads.
//   - Non-temporal float4 stores for out: output is never re-read; keeps the
//     input's L3 residency uncontested (round-1 counters showed the phase-3
//     input re-read is 100% L3-served; protect that).
//   Numerics bit-identical to v3 (same tau accumulation order, same elem fn).

#define NPART 2048
#define K2_BLOCKS 2048
#define E_F 2.7182818f
#define NEG_INV_E (-0.36787942f)

typedef float float4n __attribute__((ext_vector_type(4)));

__device__ __forceinline__ float fast_rcp(float x) {
    return __builtin_amdgcn_rcpf(x);
}

__device__ __forceinline__ float superloss_elem(float l, float tau) {
    float d = l - tau;
    float t5 = 5.0f * d;
    float y = fmaxf(NEG_INV_E, t5);
    // p = sqrt(2*(e*y + 1)); clamp tiny negative from fp rounding at branch pt
    float ey1 = fmaf(E_F, y, 1.0f);
    float p2 = fmaxf(ey1 + ey1, 0.0f);
    float p = __builtin_amdgcn_sqrtf(p2);
    // Pade[2/2] for (w+1)/p
    float num = fmaf(p, fmaf(p, 0.018055f, 0.5f), 1.0f);
    float den = fmaf(p, fmaf(p, 0.143051f, 0.833323f), 1.0f);
    float wp1 = p * num * fast_rcp(den);     // w0 + 1 >= 0
    float w = wp1 - 1.0f;
    // One Newton step: w -= (w e^w - y) / (e^w (w+1))
    // Guard +1e-4: near branch f is rounding noise (~3e-8) while den2 -> 0;
    // 1e-4 caps the spurious step at ~3e-4 where dout/dw = 0.2*(w+1) ~ 0.
    float ew = __expf(w);
    float f = fmaf(w, ew, -y);
    float den2 = fmaf(ew, wp1, 1e-4f);
    w = fmaf(-f, fast_rcp(den2), w);
    float out_u = 0.1f * (w * (w + 2.0f));   // w/5 + 0.1 w^2
    float out_c = fmaf(E_F, d, 0.1f);        // clamped: sigma = e, w = -1
    return (t5 < NEG_INV_E) ? out_c : out_u;
}

// ---- K1: block partial sums (2048 partials in ws) ----
__global__ __launch_bounds__(256) void reduce_partial(
    const float4* __restrict__ x, float* __restrict__ partials,
    int n4, const float* __restrict__ x_scalar, int n) {
    float s = 0.0f;
    int stride = gridDim.x * blockDim.x;
    int i = blockIdx.x * blockDim.x + threadIdx.x;
    // Unrolled-by-4 main stretch: 4 outstanding float4 loads per thread.
    for (; i + 3 * stride < n4; i += 4 * stride) {
        float4 a = x[i];
        float4 b = x[i + stride];
        float4 c = x[i + 2 * stride];
        float4 d = x[i + 3 * stride];
        float sa = (a.x + a.y) + (a.z + a.w);
        float sb = (b.x + b.y) + (b.z + b.w);
        float sc = (c.x + c.y) + (c.z + c.w);
        float sd = (d.x + d.y) + (d.z + d.w);
        s += (sa + sb) + (sc + sd);
    }
    for (; i < n4; i += stride) {
        float4 v = x[i];
        s += (v.x + v.y) + (v.z + v.w);
    }
    if (blockIdx.x == 0 && threadIdx.x == 0) {
        for (int j = 4 * n4; j < n; ++j) s += x_scalar[j];
    }
#pragma unroll
    for (int off = 32; off > 0; off >>= 1) s += __shfl_down(s, off, 64);
    __shared__ float smem[4];
    int lane = threadIdx.x & 63;
    int wave = threadIdx.x >> 6;
    if (lane == 0) smem[wave] = s;
    __syncthreads();
    if (threadIdx.x == 0) {
        partials[blockIdx.x] = (smem[0] + smem[1]) + (smem[2] + smem[3]);
    }
}

// ---- K2: redundant tau reduce (same order as v3) + elementwise ----
__global__ __launch_bounds__(256) void superloss_all(
    const float4* __restrict__ x, float4n* __restrict__ out,
    const float* __restrict__ partials,
    const float* __restrict__ x_s, float* __restrict__ out_s,
    int n4, int n)
{
    // Prologue: every block computes tau from the 2048 partials.
    // Same accumulation order as v3's prologue / the old finalize_tau kernel
    // -> identical bits, deterministic across blocks.
    double s = 0.0;
    for (int i = threadIdx.x; i < NPART; i += 256) s += (double)partials[i];
#pragma unroll
    for (int off = 32; off > 0; off >>= 1) s += __shfl_down(s, off, 64);
    __shared__ double dsm[4];
    int lane = threadIdx.x & 63;
    int wave = threadIdx.x >> 6;
    if (lane == 0) dsm[wave] = s;
    __syncthreads();
    __shared__ float tau_sh;
    if (threadIdx.x == 0) {
        double total = (dsm[0] + dsm[1]) + (dsm[2] + dsm[3]);
        tau_sh = (float)(total / (double)n);
    }
    __syncthreads();
    const float tau = tau_sh;

    // Elementwise pass: input re-read is L3-resident from K1's stream.
    const int stride = gridDim.x * blockDim.x;
    int i = blockIdx.x * blockDim.x + threadIdx.x;
    // Unrolled-by-2: 2 outstanding float4 loads while the VALU chews.
    for (; i + stride < n4; i += 2 * stride) {
        float4 v0 = x[i];
        float4 v1 = x[i + stride];
        float4n r0, r1;
        r0.x = superloss_elem(v0.x, tau);
        r0.y = superloss_elem(v0.y, tau);
        r0.z = superloss_elem(v0.z, tau);
        r0.w = superloss_elem(v0.w, tau);
        r1.x = superloss_elem(v1.x, tau);
        r1.y = superloss_elem(v1.y, tau);
        r1.z = superloss_elem(v1.z, tau);
        r1.w = superloss_elem(v1.w, tau);
        __builtin_nontemporal_store(r0, &out[i]);
        __builtin_nontemporal_store(r1, &out[i + stride]);
    }
    for (; i < n4; i += stride) {
        float4 v = x[i];
        float4n r;
        r.x = superloss_elem(v.x, tau);
        r.y = superloss_elem(v.y, tau);
        r.z = superloss_elem(v.z, tau);
        r.w = superloss_elem(v.w, tau);
        __builtin_nontemporal_store(r, &out[i]);
    }
    for (int j = 4 * n4 + blockIdx.x * blockDim.x + threadIdx.x; j < n; j += stride) {
        out_s[j] = superloss_elem(x_s[j], tau);
    }
}

extern "C" void kernel_launch(void* const* d_in, const int* in_sizes, int n_in,
                              void* d_out, int out_size, void* d_ws, size_t ws_size,
                              hipStream_t stream) {
    const float* loss = (const float*)d_in[0];
    float* out = (float*)d_out;
    int n = in_sizes[0];
    int n4 = n / 4;
    float* ws = (float*)d_ws;          // ws[0..NPART-1] partials

    reduce_partial<<<NPART, 256, 0, stream>>>((const float4*)loss, ws, n4, loss, n);

    superloss_all<<<K2_BLOCKS, 256, 0, stream>>>(
        (const float4*)loss, (float4n*)out, ws, loss, out, n4, n);
}

// Round 5
// 245.265 us; speedup vs baseline: 1.0312x; 1.0312x over previous
//
#include <hip/hip_runtime.h>
#include <math.h>

// SuperLoss: tau = mean(loss); y = max(-1/e, 5d), d = l - tau;
// w = W0(y); unclamped: out = d*e^{-w} + 0.1 w^2 = 0.1*w*(w+2)  [w e^w = y = 5d]
// clamped (5d < -1/e): w = -1, sigma = e -> out = e*d + 0.1  (exact closed form)
//
// W0 via single Pade[2/2] init in branch variable p = sqrt(2(e*y+1)):
//   (w+1)/p ~= (1 + 0.5p + 0.018055p^2)/(1 + 0.833323p + 0.143051p^2)
// max init err 0.0133 over p in [0,3.95]; one Newton step -> <= 7e-5.
//
// v5 = v3 (best verified: 244.9 us, tied with round-0's 243.9 within noise).
// A/B history:
//   v2 cooperative fused (grid.sync): 334 us  -- barrier stalls back half
//   v3 two-kernel (this):             244.9 us
//   v4b +nt-stores +2048-blk K2:      252.9 us -- both tweaks neutral/negative
// Controllable slice (~55-70 us of HBM/L3 traffic) is at its memory floor;
// the rest of the timed window is harness fill/restore dispatches.
//   K1: 2048-block grid-stride fp32 partial sums -> ws[0..2047]
//   K2: every block redundantly double-reduces the 2048 partials (8 KB, L2/L3
//       resident; bit-identical order to the old finalize_tau so tau is
//       unchanged), then elementwise float4 grid-stride.

#define NPART 2048
#define K2_BLOCKS 8192
#define E_F 2.7182818f
#define NEG_INV_E (-0.36787942f)

__device__ __forceinline__ float fast_rcp(float x) {
    return __builtin_amdgcn_rcpf(x);
}

__device__ __forceinline__ float superloss_elem(float l, float tau) {
    float d = l - tau;
    float t5 = 5.0f * d;
    float y = fmaxf(NEG_INV_E, t5);
    // p = sqrt(2*(e*y + 1)); clamp tiny negative from fp rounding at branch pt
    float ey1 = fmaf(E_F, y, 1.0f);
    float p2 = fmaxf(ey1 + ey1, 0.0f);
    float p = __builtin_amdgcn_sqrtf(p2);
    // Pade[2/2] for (w+1)/p
    float num = fmaf(p, fmaf(p, 0.018055f, 0.5f), 1.0f);
    float den = fmaf(p, fmaf(p, 0.143051f, 0.833323f), 1.0f);
    float wp1 = p * num * fast_rcp(den);     // w0 + 1 >= 0
    float w = wp1 - 1.0f;
    // One Newton step: w -= (w e^w - y) / (e^w (w+1))
    // Guard +1e-4: near branch f is rounding noise (~3e-8) while den2 -> 0;
    // 1e-4 caps the spurious step at ~3e-4 where dout/dw = 0.2*(w+1) ~ 0.
    float ew = __expf(w);
    float f = fmaf(w, ew, -y);
    float den2 = fmaf(ew, wp1, 1e-4f);
    w = fmaf(-f, fast_rcp(den2), w);
    float out_u = 0.1f * (w * (w + 2.0f));   // w/5 + 0.1 w^2
    float out_c = fmaf(E_F, d, 0.1f);        // clamped: sigma = e, w = -1
    return (t5 < NEG_INV_E) ? out_c : out_u;
}

// ---- K1: block partial sums (2048 partials in ws) ----
__global__ void reduce_partial(const float4* __restrict__ x, float* __restrict__ partials,
                               int n4, const float* __restrict__ x_scalar, int n) {
    float s = 0.0f;
    int stride = gridDim.x * blockDim.x;
    for (int i = blockIdx.x * blockDim.x + threadIdx.x; i < n4; i += stride) {
        float4 v = x[i];
        s += (v.x + v.y) + (v.z + v.w);
    }
    if (blockIdx.x == 0 && threadIdx.x == 0) {
        for (int i = 4 * n4; i < n; ++i) s += x_scalar[i];
    }
#pragma unroll
    for (int off = 32; off > 0; off >>= 1) s += __shfl_down(s, off, 64);
    __shared__ float smem[4];
    int lane = threadIdx.x & 63;
    int wave = threadIdx.x >> 6;
    if (lane == 0) smem[wave] = s;
    __syncthreads();
    if (threadIdx.x == 0) {
        partials[blockIdx.x] = (smem[0] + smem[1]) + (smem[2] + smem[3]);
    }
}

// ---- K2: redundant tau reduce (bit-identical to old finalize_tau) + elementwise ----
__global__ __launch_bounds__(256) void superloss_all(
    const float4* __restrict__ x, float4* __restrict__ out,
    const float* __restrict__ partials,
    const float* __restrict__ x_s, float* __restrict__ out_s,
    int n4, int n)
{
    // Prologue: every block computes tau from the 2048 partials.
    // Same accumulation order as the old finalize_tau kernel -> same bits,
    // and identical across blocks (deterministic).
    double s = 0.0;
    for (int i = threadIdx.x; i < NPART; i += 256) s += (double)partials[i];
#pragma unroll
    for (int off = 32; off > 0; off >>= 1) s += __shfl_down(s, off, 64);
    __shared__ double dsm[4];
    int lane = threadIdx.x & 63;
    int wave = threadIdx.x >> 6;
    if (lane == 0) dsm[wave] = s;
    __syncthreads();
    __shared__ float tau_sh;
    if (threadIdx.x == 0) {
        double total = (dsm[0] + dsm[1]) + (dsm[2] + dsm[3]);
        tau_sh = (float)(total / (double)n);
    }
    __syncthreads();
    const float tau = tau_sh;

    // Elementwise pass: input is L3-resident from K1's stream.
    const int stride = gridDim.x * blockDim.x;
    for (int i = blockIdx.x * blockDim.x + threadIdx.x; i < n4; i += stride) {
        float4 v = x[i];
        float4 r;
        r.x = superloss_elem(v.x, tau);
        r.y = superloss_elem(v.y, tau);
        r.z = superloss_elem(v.z, tau);
        r.w = superloss_elem(v.w, tau);
        out[i] = r;
    }
    for (int i = 4 * n4 + blockIdx.x * blockDim.x + threadIdx.x; i < n; i += stride) {
        out_s[i] = superloss_elem(x_s[i], tau);
    }
}

extern "C" void kernel_launch(void* const* d_in, const int* in_sizes, int n_in,
                              void* d_out, int out_size, void* d_ws, size_t ws_size,
                              hipStream_t stream) {
    const float* loss = (const float*)d_in[0];
    float* out = (float*)d_out;
    int n = in_sizes[0];
    int n4 = n / 4;
    float* ws = (float*)d_ws;          // ws[0..NPART-1] partials

    reduce_partial<<<NPART, 256, 0, stream>>>((const float4*)loss, ws, n4, loss, n);

    superloss_all<<<K2_BLOCKS, 256, 0, stream>>>(
        (const float4*)loss, (float4*)out, ws, loss, out, n4, n);
}